// Round 1
// baseline (23118.250 us; speedup 1.0000x reference)
//
#include <hip/hip_runtime.h>
#include <hip/hip_bf16.h>

// Problem: T=8192 steps, D_IN=2048, D=512 dense, H=512 cell, A=18 actions.
// out = concat(policy [T,18], value [T,1], hT [1,512]) fp32, 156160 elems.

#define T_STEPS 8192
#define DIN 2048
#define DD 512
#define HHH 512
#define AACT 18
#define H3 1536
#define NWG 16

typedef __attribute__((ext_vector_type(8))) short short8;
typedef __attribute__((ext_vector_type(4))) float f32x4;

// ---------------------------------------------------------------- casts
__global__ void cast_f32_bf16(const float* __restrict__ in,
                              __hip_bfloat16* __restrict__ out, int n)
{
    int i = blockIdx.x * 256 + threadIdx.x;
    if (i < n) out[i] = __float2bfloat16(in[i]);
}

// ---------------------------------------------------------------- GEMM
// C[M,N] = act(A[M,K] @ B[K,N] + bias). A either fp32 (cast on stage) or bf16.
// Block 256 (4 waves), tile 64x64, K-tile 32. Wave w computes rows [16w,16w+16).
// MFMA 16x16x32 bf16: A frag A[m=lane&15][k=quad*8+j]; B frag B[k=quad*8+j][n=lane&15];
// D: col=lane&15, row=quad*4+reg  (verified layouts per guide m89/m91/m120).
__global__ __launch_bounds__(256) void gemm_bf16(
    const float* __restrict__ A32, const __hip_bfloat16* __restrict__ A16,
    const __hip_bfloat16* __restrict__ B, const float* __restrict__ bias,
    __hip_bfloat16* __restrict__ Cb, float* __restrict__ Cf,
    int M, int N, int K, int relu)
{
    const int m0 = blockIdx.x * 64;
    const int n0 = blockIdx.y * 64;
    const int t  = threadIdx.x;
    const int wave = t >> 6;
    const int lane = t & 63;
    const int quad = lane >> 4;
    const int l16  = lane & 15;

    // pad rows to 40 bf16 (80B): keeps 16B alignment for b128 and ~2-way banks
    __shared__ __align__(16) __hip_bfloat16 As[64 * 40];
    __shared__ __align__(16) __hip_bfloat16 Bs[64 * 40];

    f32x4 acc[4];
#pragma unroll
    for (int c = 0; c < 4; ++c) acc[c] = (f32x4){0.f, 0.f, 0.f, 0.f};

    const int ar = t >> 2, akc = (t & 3) * 8;   // A stage: 8 contig bf16/thread
    const int bk = t >> 3, bn  = (t & 7) * 8;   // B stage: 8 contig along n

    for (int kb = 0; kb < K; kb += 32) {
        if (A32) {
            const float* src = A32 + (size_t)(m0 + ar) * K + kb + akc;
            float4 f0 = *(const float4*)(src);
            float4 f1 = *(const float4*)(src + 4);
            union { short8 v; __hip_bfloat16 h[8]; } u;
            u.h[0] = __float2bfloat16(f0.x); u.h[1] = __float2bfloat16(f0.y);
            u.h[2] = __float2bfloat16(f0.z); u.h[3] = __float2bfloat16(f0.w);
            u.h[4] = __float2bfloat16(f1.x); u.h[5] = __float2bfloat16(f1.y);
            u.h[6] = __float2bfloat16(f1.z); u.h[7] = __float2bfloat16(f1.w);
            *(short8*)&As[ar * 40 + akc] = u.v;
        } else {
            const __hip_bfloat16* src = A16 + (size_t)(m0 + ar) * K + kb + akc;
            *(short8*)&As[ar * 40 + akc] = *(const short8*)src;
        }
        {
            // B row-major [K][N]; store transposed Bs[n][k]
            const __hip_bfloat16* src = B + (size_t)(kb + bk) * N + n0 + bn;
            short8 v = *(const short8*)src;
            const __hip_bfloat16* vh = (const __hip_bfloat16*)&v;
#pragma unroll
            for (int i = 0; i < 8; ++i) Bs[(bn + i) * 40 + bk] = vh[i];
        }
        __syncthreads();

        short8 a = *(const short8*)&As[(wave * 16 + l16) * 40 + quad * 8];
#pragma unroll
        for (int c = 0; c < 4; ++c) {
            short8 b = *(const short8*)&Bs[(c * 16 + l16) * 40 + quad * 8];
            acc[c] = __builtin_amdgcn_mfma_f32_16x16x32_bf16(a, b, acc[c], 0, 0, 0);
        }
        __syncthreads();
    }

#pragma unroll
    for (int c = 0; c < 4; ++c) {
        const int col = n0 + c * 16 + l16;
        const float bb = bias ? bias[col] : 0.f;
#pragma unroll
        for (int r = 0; r < 4; ++r) {
            const int row = m0 + wave * 16 + quad * 4 + r;
            float v = acc[c][r] + bb;
            if (relu) v = fmaxf(v, 0.f);
            if (Cb) Cb[(size_t)row * N + col] = __float2bfloat16(v);
            if (Cf) Cf[(size_t)row * N + col] = v;
        }
    }
}

// ---------------------------------------------------------------- GRU scan
// 16 persistent WGs x 256 threads. WG i owns h slice [32i, 32i+32).
// Thread t: j_loc = t>>3 (0..31), kp = t&7 (k-range [64kp,64kp+64)).
// Each thread holds 3x64 fp32 Ug weights in VGPRs (z/r/h gate columns).
// Cross-WG: double-buffered h in global + monotonic counter barrier,
// agent-scope atomics (per-XCD L2 non-coherence).
__global__ __launch_bounds__(256, 1) void scan_kernel(
    const float* __restrict__ X,    // [T][1536] = z@Wg + bg[0]
    const float* __restrict__ Ug,   // [512][1536]
    const float* __restrict__ bg,   // [2][1536]; row 1 = recurrent bias
    const float* __restrict__ h0,   // [512] prev_hidden
    float* __restrict__ seq,        // [T][512]
    float* __restrict__ hglob,      // [2][512]
    unsigned int* __restrict__ bar, // monotonic barrier counter (memset 0)
    float* __restrict__ hT)         // [512] -> d_out tail
{
    const int t = threadIdx.x;
    const int wg = blockIdx.x;
    const int j_loc = t >> 3;
    const int kp = t & 7;
    const int j = wg * 32 + j_loc;
    const int k0 = kp * 64;

    // h staged per step; stride 68 words: bank = (4*kp+m)%32 -> conflict-free b128
    __shared__ __align__(16) float h_lds[8 * 68];

    float wz[64], wr[64], wh[64];
#pragma unroll
    for (int m = 0; m < 64; ++m) {
        const float* row = Ug + (size_t)(k0 + m) * H3;
        wz[m] = row[j];
        wr[m] = row[512 + j];
        wh[m] = row[1024 + j];
    }
    const float* brec = bg + H3;
    const float bz = brec[j], brr = brec[512 + j], bh = brec[1024 + j];
    float hj = h0[j];  // my h element (used by kp==0 lanes)

    // prefetch X[0]
    float xz = 0.f, xr = 0.f, xh = 0.f;
    if (kp == 0) { xz = X[j]; xr = X[512 + j]; xh = X[1024 + j]; }

    for (int s = 0; s < T_STEPS; ++s) {
        // ---- stage h_s into LDS (agent-scope loads: bypass stale L1/L2)
        const float* hsrc = (s == 0) ? h0 : (hglob + (s & 1) * 512);
        {
            const int k1 = t, k2 = t + 256;
            float v1 = __hip_atomic_load(hsrc + k1, __ATOMIC_RELAXED, __HIP_MEMORY_SCOPE_AGENT);
            float v2 = __hip_atomic_load(hsrc + k2, __ATOMIC_RELAXED, __HIP_MEMORY_SCOPE_AGENT);
            h_lds[(k1 >> 6) * 68 + (k1 & 63)] = v1;
            h_lds[(k2 >> 6) * 68 + (k2 & 63)] = v2;
        }
        __syncthreads();

        // ---- prefetch X[s+1] while matvec runs
        float nxz = 0.f, nxr = 0.f, nxh = 0.f;
        if (kp == 0 && s + 1 < T_STEPS) {
            const float* Xs = X + (size_t)(s + 1) * H3;
            nxz = Xs[j]; nxr = Xs[512 + j]; nxh = Xs[1024 + j];
        }

        // ---- partial matvec: 64 k-values x 3 gate columns
        float accz = 0.f, accr = 0.f, acch = 0.f;
        const float* hb = &h_lds[kp * 68];
#pragma unroll
        for (int m = 0; m < 64; m += 4) {
            float4 hv = *(const float4*)(hb + m);
            accz = fmaf(hv.x, wz[m    ], accz);
            accz = fmaf(hv.y, wz[m + 1], accz);
            accz = fmaf(hv.z, wz[m + 2], accz);
            accz = fmaf(hv.w, wz[m + 3], accz);
            accr = fmaf(hv.x, wr[m    ], accr);
            accr = fmaf(hv.y, wr[m + 1], accr);
            accr = fmaf(hv.z, wr[m + 2], accr);
            accr = fmaf(hv.w, wr[m + 3], accr);
            acch = fmaf(hv.x, wh[m    ], acch);
            acch = fmaf(hv.y, wh[m + 1], acch);
            acch = fmaf(hv.z, wh[m + 2], acch);
            acch = fmaf(hv.w, wh[m + 3], acch);
        }
        // reduce across the 8 kp lanes (consecutive lanes in-wave)
#pragma unroll
        for (int off = 4; off; off >>= 1) {
            accz += __shfl_down(accz, off, 8);
            accr += __shfl_down(accr, off, 8);
            acch += __shfl_down(acch, off, 8);
        }

        if (kp == 0) {
            const float rz = accz + bz, rr = accr + brr, rh = acch + bh;
            const float zt = 1.f / (1.f + __expf(-(xz + rz)));
            const float rt = 1.f / (1.f + __expf(-(xr + rr)));
            const float hc = 1.f / (1.f + __expf(-(xh + rt * rh)));
            const float hn = zt * hj + (1.f - zt) * hc;
            hj = hn;
            seq[(size_t)s * HHH + j] = hn;
            __hip_atomic_store(hglob + ((s + 1) & 1) * 512 + j, hn,
                               __ATOMIC_RELAXED, __HIP_MEMORY_SCOPE_AGENT);
            if (s == T_STEPS - 1) hT[j] = hn;
        }
        xz = nxz; xr = nxr; xh = nxh;

        __syncthreads();  // all stores done + h_lds consumers done
        if (t == 0) {
            __hip_atomic_fetch_add(bar, 1u, __ATOMIC_RELEASE, __HIP_MEMORY_SCOPE_AGENT);
            const unsigned target = (unsigned)(s + 1) * NWG;
            while (__hip_atomic_load(bar, __ATOMIC_ACQUIRE, __HIP_MEMORY_SCOPE_AGENT) < target) {}
        }
        __syncthreads();
    }
}

// ---------------------------------------------------------------- heads
// One wave per timestep: 18 policy logits + 1 value, shuffle-reduced.
__global__ __launch_bounds__(64) void heads_kernel(
    const float* __restrict__ seq, const float* __restrict__ Wp,
    const float* __restrict__ bp, const float* __restrict__ Wv,
    const float* __restrict__ bv, float* __restrict__ pol,
    float* __restrict__ val)
{
    const int s = blockIdx.x;
    const int l = threadIdx.x;
    const float* h = seq + (size_t)s * HHH;

    float acc[19];
#pragma unroll
    for (int jj = 0; jj < 19; ++jj) acc[jj] = 0.f;

#pragma unroll
    for (int kk = 0; kk < 8; ++kk) {
        const int k = kk * 64 + l;
        const float hv = h[k];
        const float* wrow = Wp + (size_t)k * AACT;
#pragma unroll
        for (int jj = 0; jj < AACT; ++jj) acc[jj] = fmaf(hv, wrow[jj], acc[jj]);
        acc[18] = fmaf(hv, Wv[k], acc[18]);
    }
#pragma unroll
    for (int jj = 0; jj < 19; ++jj) {
        float v = acc[jj];
#pragma unroll
        for (int off = 32; off; off >>= 1) v += __shfl_down(v, off, 64);
        acc[jj] = v;  // lane 0 holds total
    }
    if (l == 0) {
        float lg[18], mx = -1e30f;
#pragma unroll
        for (int jj = 0; jj < AACT; ++jj) { lg[jj] = acc[jj] + bp[jj]; mx = fmaxf(mx, lg[jj]); }
        float sum = 0.f;
#pragma unroll
        for (int jj = 0; jj < AACT; ++jj) { lg[jj] = __expf(lg[jj] - mx); sum += lg[jj]; }
        const float inv = 1.f / sum;
#pragma unroll
        for (int jj = 0; jj < AACT; ++jj) pol[(size_t)s * AACT + jj] = lg[jj] * inv;
        val[s] = acc[18] + bv[0];
    }
}

// ---------------------------------------------------------------- launch
extern "C" void kernel_launch(void* const* d_in, const int* in_sizes, int n_in,
                              void* d_out, int out_size, void* d_ws, size_t ws_size,
                              hipStream_t stream)
{
    const float* x  = (const float*)d_in[0];
    const float* h0 = (const float*)d_in[1];
    const float* W1 = (const float*)d_in[2];
    const float* b1 = (const float*)d_in[3];
    const float* W2 = (const float*)d_in[4];
    const float* b2 = (const float*)d_in[5];
    const float* Wg = (const float*)d_in[6];
    const float* Ug = (const float*)d_in[7];
    const float* bg = (const float*)d_in[8];
    const float* Wp = (const float*)d_in[9];
    const float* bp = (const float*)d_in[10];
    const float* Wv = (const float*)d_in[11];
    const float* bv = (const float*)d_in[12];

    // workspace layout (total 88,084,736 B)
    char* ws = (char*)d_ws;
    __hip_bfloat16* W1b = (__hip_bfloat16*)(ws + 0);         // 2,097,152
    __hip_bfloat16* W2b = (__hip_bfloat16*)(ws + 2097152);   //   524,288
    __hip_bfloat16* Wgb = (__hip_bfloat16*)(ws + 2621440);   // 1,572,864
    __hip_bfloat16* z1b = (__hip_bfloat16*)(ws + 4194304);   // 8,388,608
    __hip_bfloat16* z2b = (__hip_bfloat16*)(ws + 12582912);  // 8,388,608
    float*          Xb  = (float*)(ws + 20971520);           // 50,331,648
    float*          seq = (float*)(ws + 71303168);           // 16,777,216
    float*          hgl = (float*)(ws + 88080384);           //     4,096
    unsigned int*   bar = (unsigned int*)(ws + 88084480);    //       256

    float* out = (float*)d_out;
    float* pol = out;
    float* val = out + (size_t)T_STEPS * AACT;
    float* hT  = out + (size_t)T_STEPS * AACT + T_STEPS;

    // barrier counter must be zeroed every call (ws re-poisoned to 0xAA)
    hipMemsetAsync(bar, 0, 256, stream);

    cast_f32_bf16<<<DIN * DD / 256, 256, 0, stream>>>(W1, W1b, DIN * DD);
    cast_f32_bf16<<<DD * DD / 256, 256, 0, stream>>>(W2, W2b, DD * DD);
    cast_f32_bf16<<<DD * H3 / 256, 256, 0, stream>>>(Wg, Wgb, DD * H3);

    dim3 blk(256);
    // z1 = relu(x @ W1 + b1)  -> bf16
    gemm_bf16<<<dim3(T_STEPS / 64, DD / 64), blk, 0, stream>>>(
        x, nullptr, W1b, b1, z1b, nullptr, T_STEPS, DD, DIN, 1);
    // z2 = relu(z1 @ W2 + b2) -> bf16
    gemm_bf16<<<dim3(T_STEPS / 64, DD / 64), blk, 0, stream>>>(
        nullptr, z1b, W2b, b2, z2b, nullptr, T_STEPS, DD, DD, 1);
    // X = z2 @ Wg + bg[0]     -> fp32
    gemm_bf16<<<dim3(T_STEPS / 64, H3 / 64), blk, 0, stream>>>(
        nullptr, z2b, Wgb, bg, nullptr, Xb, T_STEPS, H3, DD, 0);

    scan_kernel<<<NWG, 256, 0, stream>>>(Xb, Ug, bg, h0, seq, hgl, bar, hT);

    heads_kernel<<<T_STEPS, 64, 0, stream>>>(seq, Wp, bp, Wv, bv, pol, val);
}

// Round 2
// 15550.540 us; speedup vs baseline: 1.4867x; 1.4867x over previous
//
#include <hip/hip_runtime.h>
#include <hip/hip_bf16.h>

// Problem: T=8192 steps, D_IN=2048, D=512 dense, H=512 cell, A=18 actions.
// out = concat(policy [T,18], value [T,1], hT [1,512]) fp32, 156160 elems.

#define T_STEPS 8192
#define DIN 2048
#define DD 512
#define HHH 512
#define AACT 18
#define H3 1536
#define NWG 32          // each WG owns 16 rows of h

typedef __attribute__((ext_vector_type(8))) short short8;
typedef __attribute__((ext_vector_type(4))) float f32x4;

// ---------------------------------------------------------------- casts
__global__ void cast_f32_bf16(const float* __restrict__ in,
                              __hip_bfloat16* __restrict__ out, int n)
{
    int i = blockIdx.x * 256 + threadIdx.x;
    if (i < n) out[i] = __float2bfloat16(in[i]);
}

// ---------------------------------------------------------------- GEMM
// C[M,N] = act(A[M,K] @ B[K,N] + bias). A either fp32 (cast on stage) or bf16.
// Block 256 (4 waves), tile 64x64, K-tile 32.
// MFMA 16x16x32 bf16: D: col=lane&15, row=quad*4+reg (verified m89/m91).
__global__ __launch_bounds__(256) void gemm_bf16(
    const float* __restrict__ A32, const __hip_bfloat16* __restrict__ A16,
    const __hip_bfloat16* __restrict__ B, const float* __restrict__ bias,
    __hip_bfloat16* __restrict__ Cb, float* __restrict__ Cf,
    int M, int N, int K, int relu)
{
    const int m0 = blockIdx.x * 64;
    const int n0 = blockIdx.y * 64;
    const int t  = threadIdx.x;
    const int wave = t >> 6;
    const int lane = t & 63;
    const int quad = lane >> 4;
    const int l16  = lane & 15;

    __shared__ __align__(16) __hip_bfloat16 As[64 * 40];
    __shared__ __align__(16) __hip_bfloat16 Bs[64 * 40];

    f32x4 acc[4];
#pragma unroll
    for (int c = 0; c < 4; ++c) acc[c] = (f32x4){0.f, 0.f, 0.f, 0.f};

    const int ar = t >> 2, akc = (t & 3) * 8;
    const int bk = t >> 3, bn  = (t & 7) * 8;

    for (int kb = 0; kb < K; kb += 32) {
        if (A32) {
            const float* src = A32 + (size_t)(m0 + ar) * K + kb + akc;
            float4 f0 = *(const float4*)(src);
            float4 f1 = *(const float4*)(src + 4);
            union { short8 v; __hip_bfloat16 h[8]; } u;
            u.h[0] = __float2bfloat16(f0.x); u.h[1] = __float2bfloat16(f0.y);
            u.h[2] = __float2bfloat16(f0.z); u.h[3] = __float2bfloat16(f0.w);
            u.h[4] = __float2bfloat16(f1.x); u.h[5] = __float2bfloat16(f1.y);
            u.h[6] = __float2bfloat16(f1.z); u.h[7] = __float2bfloat16(f1.w);
            *(short8*)&As[ar * 40 + akc] = u.v;
        } else {
            const __hip_bfloat16* src = A16 + (size_t)(m0 + ar) * K + kb + akc;
            *(short8*)&As[ar * 40 + akc] = *(const short8*)src;
        }
        {
            const __hip_bfloat16* src = B + (size_t)(kb + bk) * N + n0 + bn;
            short8 v = *(const short8*)src;
            const __hip_bfloat16* vh = (const __hip_bfloat16*)&v;
#pragma unroll
            for (int i = 0; i < 8; ++i) Bs[(bn + i) * 40 + bk] = vh[i];
        }
        __syncthreads();

        short8 a = *(const short8*)&As[(wave * 16 + l16) * 40 + quad * 8];
#pragma unroll
        for (int c = 0; c < 4; ++c) {
            short8 b = *(const short8*)&Bs[(c * 16 + l16) * 40 + quad * 8];
            acc[c] = __builtin_amdgcn_mfma_f32_16x16x32_bf16(a, b, acc[c], 0, 0, 0);
        }
        __syncthreads();
    }

#pragma unroll
    for (int c = 0; c < 4; ++c) {
        const int col = n0 + c * 16 + l16;
        const float bb = bias ? bias[col] : 0.f;
#pragma unroll
        for (int r = 0; r < 4; ++r) {
            const int row = m0 + wave * 16 + quad * 4 + r;
            float v = acc[c][r] + bb;
            if (relu) v = fmaxf(v, 0.f);
            if (Cb) Cb[(size_t)row * N + col] = __float2bfloat16(v);
            if (Cf) Cf[(size_t)row * N + col] = v;
        }
    }
}

// ---------------------------------------------------------------- GRU scan
// 32 persistent WGs x 256 threads. WG i owns h rows [16i, 16i+16).
// Thread t: jl = t>>4 (0..15), kp = t&15 (k range [32kp, 32kp+32)).
// Each thread holds 3x32 fp32 Ug weights in VGPRs (z/r/h gate columns).
// Cross-WG sync: h published as 8-byte {f32 val, u32 step} atomics,
// double-buffered by step parity; consumers spin on the tags directly.
// No separate barrier -> single global round-trip per step.
__global__ __launch_bounds__(256, 1) void scan_kernel(
    const float* __restrict__ X,            // [T][1536] = z@Wg + bg[0]
    const float* __restrict__ Ug,           // [512][1536]
    const float* __restrict__ bg,           // [2][1536]; row 1 = recurrent bias
    const float* __restrict__ h0,           // [512] prev_hidden
    float* __restrict__ seq,                // [T][512]
    unsigned long long* __restrict__ hbuf,  // [2][512] tagged h (no init needed)
    float* __restrict__ hT)                 // [512] -> d_out tail
{
    const int t  = threadIdx.x;
    const int wg = blockIdx.x;
    const int jl = t >> 4;
    const int kp = t & 15;
    const int j  = wg * 16 + jl;
    const int k0 = kp * 32;

    // double-buffered h stage; row stride 36 words = 144B (16B aligned,
    // b128 reads across 16 kp-lanes hit each bank 2-way = free)
    __shared__ __align__(16) float h_lds[2][16 * 36];

    float wz[32], wr[32], wh[32];
#pragma unroll
    for (int m = 0; m < 32; ++m) {
        const float* row = Ug + (size_t)(k0 + m) * H3;
        wz[m] = row[j];
        wr[m] = row[512 + j];
        wh[m] = row[1024 + j];
    }
    const float* brec = bg + H3;
    const float bz = brec[j], brr = brec[512 + j], bh = brec[1024 + j];
    float hj = h0[j];  // my h element (kp==0 lanes)

    // staging slots for this thread
    const int k1 = t, k2 = t + 256;
    const int a1 = (k1 >> 5) * 36 + (k1 & 31);
    const int a2 = (k2 >> 5) * 36 + (k2 & 31);

    // prefetch X[0]
    float xz = 0.f, xr = 0.f, xh = 0.f;
    if (kp == 0) { xz = X[j]; xr = X[512 + j]; xh = X[1024 + j]; }

    for (int s = 0; s < T_STEPS; ++s) {
        float* hl = h_lds[s & 1];

        // ---- acquire h_s (spin on tagged slots), stage into LDS
        if (s == 0) {
            hl[a1] = h0[k1];
            hl[a2] = h0[k2];
        } else {
            const unsigned long long* src = hbuf + (size_t)(s & 1) * 512;
            unsigned long long v1 = __hip_atomic_load(src + k1, __ATOMIC_RELAXED, __HIP_MEMORY_SCOPE_AGENT);
            while ((unsigned)(v1 >> 32) != (unsigned)s)
                v1 = __hip_atomic_load(src + k1, __ATOMIC_RELAXED, __HIP_MEMORY_SCOPE_AGENT);
            unsigned long long v2 = __hip_atomic_load(src + k2, __ATOMIC_RELAXED, __HIP_MEMORY_SCOPE_AGENT);
            while ((unsigned)(v2 >> 32) != (unsigned)s)
                v2 = __hip_atomic_load(src + k2, __ATOMIC_RELAXED, __HIP_MEMORY_SCOPE_AGENT);
            hl[a1] = __uint_as_float((unsigned)v1);
            hl[a2] = __uint_as_float((unsigned)v2);
        }
        __syncthreads();

        // ---- prefetch X[s+1] while matvec runs
        float nxz = 0.f, nxr = 0.f, nxh = 0.f;
        if (kp == 0 && s + 1 < T_STEPS) {
            const float* Xs = X + (size_t)(s + 1) * H3;
            nxz = Xs[j]; nxr = Xs[512 + j]; nxh = Xs[1024 + j];
        }

        // ---- partial matvec: 32 k-values x 3 gate columns
        float accz = 0.f, accr = 0.f, acch = 0.f;
        const float* hb = &hl[kp * 36];
#pragma unroll
        for (int m = 0; m < 32; m += 4) {
            float4 hv = *(const float4*)(hb + m);
            accz = fmaf(hv.x, wz[m    ], accz);
            accz = fmaf(hv.y, wz[m + 1], accz);
            accz = fmaf(hv.z, wz[m + 2], accz);
            accz = fmaf(hv.w, wz[m + 3], accz);
            accr = fmaf(hv.x, wr[m    ], accr);
            accr = fmaf(hv.y, wr[m + 1], accr);
            accr = fmaf(hv.z, wr[m + 2], accr);
            accr = fmaf(hv.w, wr[m + 3], accr);
            acch = fmaf(hv.x, wh[m    ], acch);
            acch = fmaf(hv.y, wh[m + 1], acch);
            acch = fmaf(hv.z, wh[m + 2], acch);
            acch = fmaf(hv.w, wh[m + 3], acch);
        }
        // reduce across the 16 kp lanes (contiguous in-wave)
#pragma unroll
        for (int off = 8; off; off >>= 1) {
            accz += __shfl_down(accz, off, 16);
            accr += __shfl_down(accr, off, 16);
            acch += __shfl_down(acch, off, 16);
        }

        if (kp == 0) {
            const float rz = accz + bz, rr = accr + brr, rh = acch + bh;
            const float zt = 1.f / (1.f + __expf(-(xz + rz)));
            const float rt = 1.f / (1.f + __expf(-(xr + rr)));
            const float hc = 1.f / (1.f + __expf(-(xh + rt * rh)));
            const float hn = zt * hj + (1.f - zt) * hc;
            hj = hn;
            seq[(size_t)s * HHH + j] = hn;
            // publish {value, step-tag} as one 8B atomic (parity s+1)
            unsigned long long pk =
                ((unsigned long long)(unsigned)(s + 1) << 32) | (unsigned)__float_as_uint(hn);
            __hip_atomic_store(hbuf + (size_t)((s + 1) & 1) * 512 + j, pk,
                               __ATOMIC_RELAXED, __HIP_MEMORY_SCOPE_AGENT);
            if (s == T_STEPS - 1) hT[j] = hn;
        }
        xz = nxz; xr = nxr; xh = nxh;
        // no trailing barrier: LDS double-buffered; next iter syncs after stage
    }
}

// ---------------------------------------------------------------- heads
__global__ __launch_bounds__(64) void heads_kernel(
    const float* __restrict__ seq, const float* __restrict__ Wp,
    const float* __restrict__ bp, const float* __restrict__ Wv,
    const float* __restrict__ bv, float* __restrict__ pol,
    float* __restrict__ val)
{
    const int s = blockIdx.x;
    const int l = threadIdx.x;
    const float* h = seq + (size_t)s * HHH;

    float acc[19];
#pragma unroll
    for (int jj = 0; jj < 19; ++jj) acc[jj] = 0.f;

#pragma unroll
    for (int kk = 0; kk < 8; ++kk) {
        const int k = kk * 64 + l;
        const float hv = h[k];
        const float* wrow = Wp + (size_t)k * AACT;
#pragma unroll
        for (int jj = 0; jj < AACT; ++jj) acc[jj] = fmaf(hv, wrow[jj], acc[jj]);
        acc[18] = fmaf(hv, Wv[k], acc[18]);
    }
#pragma unroll
    for (int jj = 0; jj < 19; ++jj) {
        float v = acc[jj];
#pragma unroll
        for (int off = 32; off; off >>= 1) v += __shfl_down(v, off, 64);
        acc[jj] = v;
    }
    if (l == 0) {
        float lg[18], mx = -1e30f;
#pragma unroll
        for (int jj = 0; jj < AACT; ++jj) { lg[jj] = acc[jj] + bp[jj]; mx = fmaxf(mx, lg[jj]); }
        float sum = 0.f;
#pragma unroll
        for (int jj = 0; jj < AACT; ++jj) { lg[jj] = __expf(lg[jj] - mx); sum += lg[jj]; }
        const float inv = 1.f / sum;
#pragma unroll
        for (int jj = 0; jj < AACT; ++jj) pol[(size_t)s * AACT + jj] = lg[jj] * inv;
        val[s] = acc[18] + bv[0];
    }
}

// ---------------------------------------------------------------- launch
extern "C" void kernel_launch(void* const* d_in, const int* in_sizes, int n_in,
                              void* d_out, int out_size, void* d_ws, size_t ws_size,
                              hipStream_t stream)
{
    const float* x  = (const float*)d_in[0];
    const float* h0 = (const float*)d_in[1];
    const float* W1 = (const float*)d_in[2];
    const float* b1 = (const float*)d_in[3];
    const float* W2 = (const float*)d_in[4];
    const float* b2 = (const float*)d_in[5];
    const float* Wg = (const float*)d_in[6];
    const float* Ug = (const float*)d_in[7];
    const float* bg = (const float*)d_in[8];
    const float* Wp = (const float*)d_in[9];
    const float* bp = (const float*)d_in[10];
    const float* Wv = (const float*)d_in[11];
    const float* bv = (const float*)d_in[12];

    char* ws = (char*)d_ws;
    __hip_bfloat16* W1b = (__hip_bfloat16*)(ws + 0);         // 2,097,152
    __hip_bfloat16* W2b = (__hip_bfloat16*)(ws + 2097152);   //   524,288
    __hip_bfloat16* Wgb = (__hip_bfloat16*)(ws + 2621440);   // 1,572,864
    __hip_bfloat16* z1b = (__hip_bfloat16*)(ws + 4194304);   // 8,388,608
    __hip_bfloat16* z2b = (__hip_bfloat16*)(ws + 12582912);  // 8,388,608
    float*          Xb  = (float*)(ws + 20971520);           // 50,331,648
    float*          seq = (float*)(ws + 71303168);           // 16,777,216
    unsigned long long* hbuf = (unsigned long long*)(ws + 88080384); // 8,192
    // hbuf needs NO init: step tags are self-validating vs 0xAA poison

    float* out = (float*)d_out;
    float* pol = out;
    float* val = out + (size_t)T_STEPS * AACT;
    float* hT  = out + (size_t)T_STEPS * AACT + T_STEPS;

    cast_f32_bf16<<<DIN * DD / 256, 256, 0, stream>>>(W1, W1b, DIN * DD);
    cast_f32_bf16<<<DD * DD / 256, 256, 0, stream>>>(W2, W2b, DD * DD);
    cast_f32_bf16<<<DD * H3 / 256, 256, 0, stream>>>(Wg, Wgb, DD * H3);

    dim3 blk(256);
    gemm_bf16<<<dim3(T_STEPS / 64, DD / 64), blk, 0, stream>>>(
        x, nullptr, W1b, b1, z1b, nullptr, T_STEPS, DD, DIN, 1);
    gemm_bf16<<<dim3(T_STEPS / 64, DD / 64), blk, 0, stream>>>(
        nullptr, z1b, W2b, b2, z2b, nullptr, T_STEPS, DD, DD, 1);
    gemm_bf16<<<dim3(T_STEPS / 64, H3 / 64), blk, 0, stream>>>(
        nullptr, z2b, Wgb, bg, nullptr, Xb, T_STEPS, H3, DD, 0);

    scan_kernel<<<NWG, 256, 0, stream>>>(Xb, Ug, bg, h0, seq, hbuf, hT);

    heads_kernel<<<T_STEPS, 64, 0, stream>>>(seq, Wp, bp, Wv, bv, pol, val);
}

// Round 3
// 13558.780 us; speedup vs baseline: 1.7050x; 1.1469x over previous
//
#include <hip/hip_runtime.h>
#include <hip/hip_bf16.h>

// Problem: T=8192 steps, D_IN=2048, D=512 dense, H=512 cell, A=18 actions.
// out = concat(policy [T,18], value [T,1], hT [1,512]) fp32, 156160 elems.

#define T_STEPS 8192
#define DIN 2048
#define DD 512
#define HHH 512
#define AACT 18
#define H3 1536
#define NWG 32          // each WG owns 16 rows of h

typedef __attribute__((ext_vector_type(8))) short short8;
typedef __attribute__((ext_vector_type(4))) float f32x4;

// ---------------------------------------------------------------- casts
__global__ void cast_f32_bf16(const float* __restrict__ in,
                              __hip_bfloat16* __restrict__ out, int n)
{
    int i = blockIdx.x * 256 + threadIdx.x;
    if (i < n) out[i] = __float2bfloat16(in[i]);
}

// ---------------------------------------------------------------- GEMM
// C[M,N] = act(A[M,K] @ B[K,N] + bias). A either fp32 (cast on stage) or bf16.
// Block 256 (4 waves), tile 64x64, K-tile 32.
// MFMA 16x16x32 bf16: D: col=lane&15, row=quad*4+reg (verified m89/m91).
__global__ __launch_bounds__(256) void gemm_bf16(
    const float* __restrict__ A32, const __hip_bfloat16* __restrict__ A16,
    const __hip_bfloat16* __restrict__ B, const float* __restrict__ bias,
    __hip_bfloat16* __restrict__ Cb, float* __restrict__ Cf,
    int M, int N, int K, int relu)
{
    const int m0 = blockIdx.x * 64;
    const int n0 = blockIdx.y * 64;
    const int t  = threadIdx.x;
    const int wave = t >> 6;
    const int lane = t & 63;
    const int quad = lane >> 4;
    const int l16  = lane & 15;

    __shared__ __align__(16) __hip_bfloat16 As[64 * 40];
    __shared__ __align__(16) __hip_bfloat16 Bs[64 * 40];

    f32x4 acc[4];
#pragma unroll
    for (int c = 0; c < 4; ++c) acc[c] = (f32x4){0.f, 0.f, 0.f, 0.f};

    const int ar = t >> 2, akc = (t & 3) * 8;
    const int bk = t >> 3, bn  = (t & 7) * 8;

    for (int kb = 0; kb < K; kb += 32) {
        if (A32) {
            const float* src = A32 + (size_t)(m0 + ar) * K + kb + akc;
            float4 f0 = *(const float4*)(src);
            float4 f1 = *(const float4*)(src + 4);
            union { short8 v; __hip_bfloat16 h[8]; } u;
            u.h[0] = __float2bfloat16(f0.x); u.h[1] = __float2bfloat16(f0.y);
            u.h[2] = __float2bfloat16(f0.z); u.h[3] = __float2bfloat16(f0.w);
            u.h[4] = __float2bfloat16(f1.x); u.h[5] = __float2bfloat16(f1.y);
            u.h[6] = __float2bfloat16(f1.z); u.h[7] = __float2bfloat16(f1.w);
            *(short8*)&As[ar * 40 + akc] = u.v;
        } else {
            const __hip_bfloat16* src = A16 + (size_t)(m0 + ar) * K + kb + akc;
            *(short8*)&As[ar * 40 + akc] = *(const short8*)src;
        }
        {
            const __hip_bfloat16* src = B + (size_t)(kb + bk) * N + n0 + bn;
            short8 v = *(const short8*)src;
            const __hip_bfloat16* vh = (const __hip_bfloat16*)&v;
#pragma unroll
            for (int i = 0; i < 8; ++i) Bs[(bn + i) * 40 + bk] = vh[i];
        }
        __syncthreads();

        short8 a = *(const short8*)&As[(wave * 16 + l16) * 40 + quad * 8];
#pragma unroll
        for (int c = 0; c < 4; ++c) {
            short8 b = *(const short8*)&Bs[(c * 16 + l16) * 40 + quad * 8];
            acc[c] = __builtin_amdgcn_mfma_f32_16x16x32_bf16(a, b, acc[c], 0, 0, 0);
        }
        __syncthreads();
    }

#pragma unroll
    for (int c = 0; c < 4; ++c) {
        const int col = n0 + c * 16 + l16;
        const float bb = bias ? bias[col] : 0.f;
#pragma unroll
        for (int r = 0; r < 4; ++r) {
            const int row = m0 + wave * 16 + quad * 4 + r;
            float v = acc[c][r] + bb;
            if (relu) v = fmaxf(v, 0.f);
            if (Cb) Cb[(size_t)row * N + col] = __float2bfloat16(v);
            if (Cf) Cf[(size_t)row * N + col] = v;
        }
    }
}

// ---------------------------------------------------------------- GRU scan
// 32 persistent WGs x 256 threads. WG i owns h rows [16i, 16i+16).
// Thread t: jl = t>>4 (0..15), kp = t&15 (k range [32kp, 32kp+32)).
// Each thread holds 3x32 fp32 Ug weights PINNED in VGPRs (asm "+v" after the
// init load stops the compiler from sinking the loads into the step loop —
// R2 showed VGPR_Count=76 < 96 weights => it was re-loading from L2 each step).
// Cross-WG sync: h published as 8-byte {f32 val, u32 step} atomics,
// double-buffered by step parity; consumers spin on the tags directly.
__global__ __launch_bounds__(256, 1) void scan_kernel(
    const float* __restrict__ X,            // [T][1536] = z@Wg + bg[0]
    const float* __restrict__ Ug,           // [512][1536]
    const float* __restrict__ bg,           // [2][1536]; row 1 = recurrent bias
    const float* __restrict__ h0,           // [512] prev_hidden
    float* __restrict__ seq,                // [T][512]
    unsigned long long* __restrict__ hbuf,  // [2][512] tagged h (no init needed)
    float* __restrict__ hT)                 // [512] -> d_out tail
{
    const int t  = threadIdx.x;
    const int wg = blockIdx.x;
    const int jl = t >> 4;
    const int kp = t & 15;
    const int j  = wg * 16 + jl;
    const int k0 = kp * 32;

    // double-buffered h stage; row stride 36 words = 144B (16B aligned;
    // b128 reads across 16 kp-lanes alias banks 2-way = free per m136)
    __shared__ __align__(16) float h_lds[2][16 * 36];

    float wz[32], wr[32], wh[32];
#pragma unroll
    for (int m = 0; m < 32; ++m) {
        const float* row = Ug + (size_t)(k0 + m) * H3;
        wz[m] = row[j];
        wr[m] = row[512 + j];
        wh[m] = row[1024 + j];
    }
    // pin all 96 weights into VGPRs: opaque def the compiler cannot
    // rematerialize by re-loading from Ug inside the step loop
#pragma unroll
    for (int m = 0; m < 32; ++m) {
        asm volatile("" : "+v"(wz[m]), "+v"(wr[m]), "+v"(wh[m]));
    }

    const float* brec = bg + H3;
    const float bz = brec[j], brr = brec[512 + j], bh = brec[1024 + j];
    float hj = h0[j];  // my h element (kp==0 lanes)

    // staging slots for this thread
    const int k1 = t, k2 = t + 256;
    const int a1 = (k1 >> 5) * 36 + (k1 & 31);
    const int a2 = (k2 >> 5) * 36 + (k2 & 31);

    // prefetch X[0]
    float xz = 0.f, xr = 0.f, xh = 0.f;
    if (kp == 0) { xz = X[j]; xr = X[512 + j]; xh = X[1024 + j]; }

    for (int s = 0; s < T_STEPS; ++s) {
        float* hl = h_lds[s & 1];

        // ---- acquire h_s (spin on tagged slots, both polls in flight)
        if (s == 0) {
            hl[a1] = h0[k1];
            hl[a2] = h0[k2];
        } else {
            const unsigned long long* src = hbuf + (size_t)(s & 1) * 512;
            unsigned long long v1 = __hip_atomic_load(src + k1, __ATOMIC_RELAXED, __HIP_MEMORY_SCOPE_AGENT);
            unsigned long long v2 = __hip_atomic_load(src + k2, __ATOMIC_RELAXED, __HIP_MEMORY_SCOPE_AGENT);
            bool ok1 = (unsigned)(v1 >> 32) == (unsigned)s;
            bool ok2 = (unsigned)(v2 >> 32) == (unsigned)s;
            while (!(ok1 && ok2)) {
                if (!ok1) v1 = __hip_atomic_load(src + k1, __ATOMIC_RELAXED, __HIP_MEMORY_SCOPE_AGENT);
                if (!ok2) v2 = __hip_atomic_load(src + k2, __ATOMIC_RELAXED, __HIP_MEMORY_SCOPE_AGENT);
                ok1 = (unsigned)(v1 >> 32) == (unsigned)s;
                ok2 = (unsigned)(v2 >> 32) == (unsigned)s;
            }
            hl[a1] = __uint_as_float((unsigned)v1);
            hl[a2] = __uint_as_float((unsigned)v2);
        }
        __syncthreads();

        // ---- prefetch X[s+1] while matvec runs
        float nxz = 0.f, nxr = 0.f, nxh = 0.f;
        if (kp == 0 && s + 1 < T_STEPS) {
            const float* Xs = X + (size_t)(s + 1) * H3;
            nxz = Xs[j]; nxr = Xs[512 + j]; nxh = Xs[1024 + j];
        }

        // ---- partial matvec: 32 k-values x 3 gate columns
        float accz = 0.f, accr = 0.f, acch = 0.f;
        const float* hb = &hl[kp * 36];
#pragma unroll
        for (int m = 0; m < 32; m += 4) {
            float4 hv = *(const float4*)(hb + m);
            accz = fmaf(hv.x, wz[m    ], accz);
            accz = fmaf(hv.y, wz[m + 1], accz);
            accz = fmaf(hv.z, wz[m + 2], accz);
            accz = fmaf(hv.w, wz[m + 3], accz);
            accr = fmaf(hv.x, wr[m    ], accr);
            accr = fmaf(hv.y, wr[m + 1], accr);
            accr = fmaf(hv.z, wr[m + 2], accr);
            accr = fmaf(hv.w, wr[m + 3], accr);
            acch = fmaf(hv.x, wh[m    ], acch);
            acch = fmaf(hv.y, wh[m + 1], acch);
            acch = fmaf(hv.z, wh[m + 2], acch);
            acch = fmaf(hv.w, wh[m + 3], acch);
        }
        // reduce across the 16 kp lanes (contiguous in-wave)
#pragma unroll
        for (int off = 8; off; off >>= 1) {
            accz += __shfl_down(accz, off, 16);
            accr += __shfl_down(accr, off, 16);
            acch += __shfl_down(acch, off, 16);
        }

        if (kp == 0) {
            const float rz = accz + bz, rr = accr + brr, rh = acch + bh;
            const float zt = 1.f / (1.f + __expf(-(xz + rz)));
            const float rt = 1.f / (1.f + __expf(-(xr + rr)));
            const float hc = 1.f / (1.f + __expf(-(xh + rt * rh)));
            const float hn = zt * hj + (1.f - zt) * hc;
            hj = hn;
            seq[(size_t)s * HHH + j] = hn;
            // publish {value, step-tag} as one 8B atomic (parity s+1)
            unsigned long long pk =
                ((unsigned long long)(unsigned)(s + 1) << 32) | (unsigned)__float_as_uint(hn);
            __hip_atomic_store(hbuf + (size_t)((s + 1) & 1) * 512 + j, pk,
                               __ATOMIC_RELAXED, __HIP_MEMORY_SCOPE_AGENT);
            if (s == T_STEPS - 1) hT[j] = hn;
        }
        xz = nxz; xr = nxr; xh = nxh;
        // no trailing barrier: LDS double-buffered; next iter syncs after stage
    }
}

// ---------------------------------------------------------------- heads
__global__ __launch_bounds__(64) void heads_kernel(
    const float* __restrict__ seq, const float* __restrict__ Wp,
    const float* __restrict__ bp, const float* __restrict__ Wv,
    const float* __restrict__ bv, float* __restrict__ pol,
    float* __restrict__ val)
{
    const int s = blockIdx.x;
    const int l = threadIdx.x;
    const float* h = seq + (size_t)s * HHH;

    float acc[19];
#pragma unroll
    for (int jj = 0; jj < 19; ++jj) acc[jj] = 0.f;

#pragma unroll
    for (int kk = 0; kk < 8; ++kk) {
        const int k = kk * 64 + l;
        const float hv = h[k];
        const float* wrow = Wp + (size_t)k * AACT;
#pragma unroll
        for (int jj = 0; jj < AACT; ++jj) acc[jj] = fmaf(hv, wrow[jj], acc[jj]);
        acc[18] = fmaf(hv, Wv[k], acc[18]);
    }
#pragma unroll
    for (int jj = 0; jj < 19; ++jj) {
        float v = acc[jj];
#pragma unroll
        for (int off = 32; off; off >>= 1) v += __shfl_down(v, off, 64);
        acc[jj] = v;
    }
    if (l == 0) {
        float lg[18], mx = -1e30f;
#pragma unroll
        for (int jj = 0; jj < AACT; ++jj) { lg[jj] = acc[jj] + bp[jj]; mx = fmaxf(mx, lg[jj]); }
        float sum = 0.f;
#pragma unroll
        for (int jj = 0; jj < AACT; ++jj) { lg[jj] = __expf(lg[jj] - mx); sum += lg[jj]; }
        const float inv = 1.f / sum;
#pragma unroll
        for (int jj = 0; jj < AACT; ++jj) pol[(size_t)s * AACT + jj] = lg[jj] * inv;
        val[s] = acc[18] + bv[0];
    }
}

// ---------------------------------------------------------------- launch
extern "C" void kernel_launch(void* const* d_in, const int* in_sizes, int n_in,
                              void* d_out, int out_size, void* d_ws, size_t ws_size,
                              hipStream_t stream)
{
    const float* x  = (const float*)d_in[0];
    const float* h0 = (const float*)d_in[1];
    const float* W1 = (const float*)d_in[2];
    const float* b1 = (const float*)d_in[3];
    const float* W2 = (const float*)d_in[4];
    const float* b2 = (const float*)d_in[5];
    const float* Wg = (const float*)d_in[6];
    const float* Ug = (const float*)d_in[7];
    const float* bg = (const float*)d_in[8];
    const float* Wp = (const float*)d_in[9];
    const float* bp = (const float*)d_in[10];
    const float* Wv = (const float*)d_in[11];
    const float* bv = (const float*)d_in[12];

    char* ws = (char*)d_ws;
    __hip_bfloat16* W1b = (__hip_bfloat16*)(ws + 0);         // 2,097,152
    __hip_bfloat16* W2b = (__hip_bfloat16*)(ws + 2097152);   //   524,288
    __hip_bfloat16* Wgb = (__hip_bfloat16*)(ws + 2621440);   // 1,572,864
    __hip_bfloat16* z1b = (__hip_bfloat16*)(ws + 4194304);   // 8,388,608
    __hip_bfloat16* z2b = (__hip_bfloat16*)(ws + 12582912);  // 8,388,608
    float*          Xb  = (float*)(ws + 20971520);           // 50,331,648
    float*          seq = (float*)(ws + 71303168);           // 16,777,216
    unsigned long long* hbuf = (unsigned long long*)(ws + 88080384); // 8,192
    // hbuf needs NO init: step tags are self-validating vs 0xAA poison

    float* out = (float*)d_out;
    float* pol = out;
    float* val = out + (size_t)T_STEPS * AACT;
    float* hT  = out + (size_t)T_STEPS * AACT + T_STEPS;

    cast_f32_bf16<<<DIN * DD / 256, 256, 0, stream>>>(W1, W1b, DIN * DD);
    cast_f32_bf16<<<DD * DD / 256, 256, 0, stream>>>(W2, W2b, DD * DD);
    cast_f32_bf16<<<DD * H3 / 256, 256, 0, stream>>>(Wg, Wgb, DD * H3);

    dim3 blk(256);
    gemm_bf16<<<dim3(T_STEPS / 64, DD / 64), blk, 0, stream>>>(
        x, nullptr, W1b, b1, z1b, nullptr, T_STEPS, DD, DIN, 1);
    gemm_bf16<<<dim3(T_STEPS / 64, DD / 64), blk, 0, stream>>>(
        nullptr, z1b, W2b, b2, z2b, nullptr, T_STEPS, DD, DD, 1);
    gemm_bf16<<<dim3(T_STEPS / 64, H3 / 64), blk, 0, stream>>>(
        nullptr, z2b, Wgb, bg, nullptr, Xb, T_STEPS, H3, DD, 0);

    scan_kernel<<<NWG, 256, 0, stream>>>(Xb, Ug, bg, h0, seq, hbuf, hT);

    heads_kernel<<<T_STEPS, 64, 0, stream>>>(seq, Wp, bp, Wv, bv, pol, val);
}

// Round 4
// 12941.827 us; speedup vs baseline: 1.7863x; 1.0477x over previous
//
#include <hip/hip_runtime.h>
#include <hip/hip_bf16.h>

// Problem: T=8192 steps, D_IN=2048, D=512 dense, H=512 cell, A=18 actions.
// out = concat(policy [T,18], value [T,1], hT [1,512]) fp32, 156160 elems.

#define T_STEPS 8192
#define DIN 2048
#define DD 512
#define HHH 512
#define AACT 18
#define H3 1536
#define NWG 32          // each WG owns 16 rows of h

typedef __attribute__((ext_vector_type(8))) short short8;
typedef __attribute__((ext_vector_type(4))) float f32x4;

// ---------------------------------------------------------------- casts
__global__ void cast_f32_bf16(const float* __restrict__ in,
                              __hip_bfloat16* __restrict__ out, int n)
{
    int i = blockIdx.x * 256 + threadIdx.x;
    if (i < n) out[i] = __float2bfloat16(in[i]);
}

// ---------------------------------------------------------------- GEMM
// C[M,N] = act(A[M,K] @ B[K,N] + bias). A either fp32 (cast on stage) or bf16.
// Block 256 (4 waves), tile 64x64, K-tile 32.
// MFMA 16x16x32 bf16: D: col=lane&15, row=quad*4+reg (verified m89/m91).
__global__ __launch_bounds__(256) void gemm_bf16(
    const float* __restrict__ A32, const __hip_bfloat16* __restrict__ A16,
    const __hip_bfloat16* __restrict__ B, const float* __restrict__ bias,
    __hip_bfloat16* __restrict__ Cb, float* __restrict__ Cf,
    int M, int N, int K, int relu)
{
    const int m0 = blockIdx.x * 64;
    const int n0 = blockIdx.y * 64;
    const int t  = threadIdx.x;
    const int wave = t >> 6;
    const int lane = t & 63;
    const int quad = lane >> 4;
    const int l16  = lane & 15;

    __shared__ __align__(16) __hip_bfloat16 As[64 * 40];
    __shared__ __align__(16) __hip_bfloat16 Bs[64 * 40];

    f32x4 acc[4];
#pragma unroll
    for (int c = 0; c < 4; ++c) acc[c] = (f32x4){0.f, 0.f, 0.f, 0.f};

    const int ar = t >> 2, akc = (t & 3) * 8;
    const int bk = t >> 3, bn  = (t & 7) * 8;

    for (int kb = 0; kb < K; kb += 32) {
        if (A32) {
            const float* src = A32 + (size_t)(m0 + ar) * K + kb + akc;
            float4 f0 = *(const float4*)(src);
            float4 f1 = *(const float4*)(src + 4);
            union { short8 v; __hip_bfloat16 h[8]; } u;
            u.h[0] = __float2bfloat16(f0.x); u.h[1] = __float2bfloat16(f0.y);
            u.h[2] = __float2bfloat16(f0.z); u.h[3] = __float2bfloat16(f0.w);
            u.h[4] = __float2bfloat16(f1.x); u.h[5] = __float2bfloat16(f1.y);
            u.h[6] = __float2bfloat16(f1.z); u.h[7] = __float2bfloat16(f1.w);
            *(short8*)&As[ar * 40 + akc] = u.v;
        } else {
            const __hip_bfloat16* src = A16 + (size_t)(m0 + ar) * K + kb + akc;
            *(short8*)&As[ar * 40 + akc] = *(const short8*)src;
        }
        {
            const __hip_bfloat16* src = B + (size_t)(kb + bk) * N + n0 + bn;
            short8 v = *(const short8*)src;
            const __hip_bfloat16* vh = (const __hip_bfloat16*)&v;
#pragma unroll
            for (int i = 0; i < 8; ++i) Bs[(bn + i) * 40 + bk] = vh[i];
        }
        __syncthreads();

        short8 a = *(const short8*)&As[(wave * 16 + l16) * 40 + quad * 8];
#pragma unroll
        for (int c = 0; c < 4; ++c) {
            short8 b = *(const short8*)&Bs[(c * 16 + l16) * 40 + quad * 8];
            acc[c] = __builtin_amdgcn_mfma_f32_16x16x32_bf16(a, b, acc[c], 0, 0, 0);
        }
        __syncthreads();
    }

#pragma unroll
    for (int c = 0; c < 4; ++c) {
        const int col = n0 + c * 16 + l16;
        const float bb = bias ? bias[col] : 0.f;
#pragma unroll
        for (int r = 0; r < 4; ++r) {
            const int row = m0 + wave * 16 + quad * 4 + r;
            float v = acc[c][r] + bb;
            if (relu) v = fmaxf(v, 0.f);
            if (Cb) Cb[(size_t)row * N + col] = __float2bfloat16(v);
            if (Cf) Cf[(size_t)row * N + col] = v;
        }
    }
}

// ---------------------------------------------------------------- GRU scan
// 32 persistent WGs x 256 threads. WG i owns h rows [16i, 16i+16).
// Thread t: jl = t>>4 (0..15), kp = t&15 (k range [32kp, 32kp+32)).
// Each thread holds 3x32 fp32 Ug weights pinned in the AGPR file ("+a" asm:
// AGPRs cannot be silently spilled to scratch; compiler inserts 1-cyc
// v_accvgpr_read per use). R3 showed VGPR_Count=76 < 96 weights => the "+v"
// pin still left per-step reloads on the critical path.
// Cross-WG sync: h published as 8-byte {f32 val, u32 step} atomics,
// double-buffered by step parity; consumers spin on the tags directly.
__global__ __launch_bounds__(256)
__attribute__((amdgpu_waves_per_eu(1, 1)))
void scan_kernel(
    const float* __restrict__ X,            // [T][1536] = z@Wg + bg[0]
    const float* __restrict__ Ug,           // [512][1536]
    const float* __restrict__ bg,           // [2][1536]; row 1 = recurrent bias
    const float* __restrict__ h0,           // [512] prev_hidden
    float* __restrict__ seq,                // [T][512]
    unsigned long long* __restrict__ hbuf,  // [2][512] tagged h (no init needed)
    float* __restrict__ hT)                 // [512] -> d_out tail
{
    const int t  = threadIdx.x;
    const int wg = blockIdx.x;
    const int jl = t >> 4;
    const int kp = t & 15;
    const int j  = wg * 16 + jl;
    const int k0 = kp * 32;

    // double-buffered h stage; row stride 36 words = 144B (16B aligned;
    // b128 reads across 16 kp-lanes alias banks 2-way = free per m136)
    __shared__ __align__(16) float h_lds[2][16 * 36];

    float wz[32], wr[32], wh[32];
#pragma unroll
    for (int m = 0; m < 32; ++m) {
        const float* row = Ug + (size_t)(k0 + m) * H3;
        wz[m] = row[j];
        wr[m] = row[512 + j];
        wh[m] = row[1024 + j];
    }
    // pin all 96 weights into AGPRs: guaranteed register residency for the
    // whole step loop (no scratch spill path exists for "a"-pinned values)
#pragma unroll
    for (int m = 0; m < 32; ++m) {
        asm volatile("" : "+a"(wz[m]), "+a"(wr[m]), "+a"(wh[m]));
    }

    const float* brec = bg + H3;
    const float bz = brec[j], brr = brec[512 + j], bh = brec[1024 + j];
    float hj = h0[j];  // my h element (kp==0 lanes)

    // staging slots for this thread
    const int k1 = t, k2 = t + 256;
    const int a1 = (k1 >> 5) * 36 + (k1 & 31);
    const int a2 = (k2 >> 5) * 36 + (k2 & 31);

    // prefetch X[0]
    float xz = 0.f, xr = 0.f, xh = 0.f;
    if (kp == 0) { xz = X[j]; xr = X[512 + j]; xh = X[1024 + j]; }

    for (int s = 0; s < T_STEPS; ++s) {
        float* hl = h_lds[s & 1];

        // ---- acquire h_s (spin on tagged slots, both polls in flight)
        if (s == 0) {
            hl[a1] = h0[k1];
            hl[a2] = h0[k2];
        } else {
            const unsigned long long* src = hbuf + (size_t)(s & 1) * 512;
            unsigned long long v1 = __hip_atomic_load(src + k1, __ATOMIC_RELAXED, __HIP_MEMORY_SCOPE_AGENT);
            unsigned long long v2 = __hip_atomic_load(src + k2, __ATOMIC_RELAXED, __HIP_MEMORY_SCOPE_AGENT);
            bool ok1 = (unsigned)(v1 >> 32) == (unsigned)s;
            bool ok2 = (unsigned)(v2 >> 32) == (unsigned)s;
            while (!(ok1 && ok2)) {
                if (!ok1) v1 = __hip_atomic_load(src + k1, __ATOMIC_RELAXED, __HIP_MEMORY_SCOPE_AGENT);
                if (!ok2) v2 = __hip_atomic_load(src + k2, __ATOMIC_RELAXED, __HIP_MEMORY_SCOPE_AGENT);
                ok1 = (unsigned)(v1 >> 32) == (unsigned)s;
                ok2 = (unsigned)(v2 >> 32) == (unsigned)s;
            }
            hl[a1] = __uint_as_float((unsigned)v1);
            hl[a2] = __uint_as_float((unsigned)v2);
        }
        __syncthreads();

        // ---- prefetch X[s+1] while matvec runs
        float nxz = 0.f, nxr = 0.f, nxh = 0.f;
        if (kp == 0 && s + 1 < T_STEPS) {
            const float* Xs = X + (size_t)(s + 1) * H3;
            nxz = Xs[j]; nxr = Xs[512 + j]; nxh = Xs[1024 + j];
        }

        // ---- partial matvec: 32 k-values x 3 gate columns
        float accz = 0.f, accr = 0.f, acch = 0.f;
        const float* hb = &hl[kp * 36];
#pragma unroll
        for (int m = 0; m < 32; m += 4) {
            float4 hv = *(const float4*)(hb + m);
            accz = fmaf(hv.x, wz[m    ], accz);
            accz = fmaf(hv.y, wz[m + 1], accz);
            accz = fmaf(hv.z, wz[m + 2], accz);
            accz = fmaf(hv.w, wz[m + 3], accz);
            accr = fmaf(hv.x, wr[m    ], accr);
            accr = fmaf(hv.y, wr[m + 1], accr);
            accr = fmaf(hv.z, wr[m + 2], accr);
            accr = fmaf(hv.w, wr[m + 3], accr);
            acch = fmaf(hv.x, wh[m    ], acch);
            acch = fmaf(hv.y, wh[m + 1], acch);
            acch = fmaf(hv.z, wh[m + 2], acch);
            acch = fmaf(hv.w, wh[m + 3], acch);
        }
        // reduce across the 16 kp lanes (contiguous in-wave)
#pragma unroll
        for (int off = 8; off; off >>= 1) {
            accz += __shfl_down(accz, off, 16);
            accr += __shfl_down(accr, off, 16);
            acch += __shfl_down(acch, off, 16);
        }

        if (kp == 0) {
            const float rz = accz + bz, rr = accr + brr, rh = acch + bh;
            const float zt = 1.f / (1.f + __expf(-(xz + rz)));
            const float rt = 1.f / (1.f + __expf(-(xr + rr)));
            const float hc = 1.f / (1.f + __expf(-(xh + rt * rh)));
            const float hn = zt * hj + (1.f - zt) * hc;
            hj = hn;
            // publish FIRST: the cross-XCD store is the critical path
            unsigned long long pk =
                ((unsigned long long)(unsigned)(s + 1) << 32) | (unsigned)__float_as_uint(hn);
            __hip_atomic_store(hbuf + (size_t)((s + 1) & 1) * 512 + j, pk,
                               __ATOMIC_RELAXED, __HIP_MEMORY_SCOPE_AGENT);
            seq[(size_t)s * HHH + j] = hn;
            if (s == T_STEPS - 1) hT[j] = hn;
        }
        xz = nxz; xr = nxr; xh = nxh;
        // no trailing barrier: LDS double-buffered; next iter syncs after stage
    }
}

// ---------------------------------------------------------------- heads
__global__ __launch_bounds__(64) void heads_kernel(
    const float* __restrict__ seq, const float* __restrict__ Wp,
    const float* __restrict__ bp, const float* __restrict__ Wv,
    const float* __restrict__ bv, float* __restrict__ pol,
    float* __restrict__ val)
{
    const int s = blockIdx.x;
    const int l = threadIdx.x;
    const float* h = seq + (size_t)s * HHH;

    float acc[19];
#pragma unroll
    for (int jj = 0; jj < 19; ++jj) acc[jj] = 0.f;

#pragma unroll
    for (int kk = 0; kk < 8; ++kk) {
        const int k = kk * 64 + l;
        const float hv = h[k];
        const float* wrow = Wp + (size_t)k * AACT;
#pragma unroll
        for (int jj = 0; jj < AACT; ++jj) acc[jj] = fmaf(hv, wrow[jj], acc[jj]);
        acc[18] = fmaf(hv, Wv[k], acc[18]);
    }
#pragma unroll
    for (int jj = 0; jj < 19; ++jj) {
        float v = acc[jj];
#pragma unroll
        for (int off = 32; off; off >>= 1) v += __shfl_down(v, off, 64);
        acc[jj] = v;
    }
    if (l == 0) {
        float lg[18], mx = -1e30f;
#pragma unroll
        for (int jj = 0; jj < AACT; ++jj) { lg[jj] = acc[jj] + bp[jj]; mx = fmaxf(mx, lg[jj]); }
        float sum = 0.f;
#pragma unroll
        for (int jj = 0; jj < AACT; ++jj) { lg[jj] = __expf(lg[jj] - mx); sum += lg[jj]; }
        const float inv = 1.f / sum;
#pragma unroll
        for (int jj = 0; jj < AACT; ++jj) pol[(size_t)s * AACT + jj] = lg[jj] * inv;
        val[s] = acc[18] + bv[0];
    }
}

// ---------------------------------------------------------------- launch
extern "C" void kernel_launch(void* const* d_in, const int* in_sizes, int n_in,
                              void* d_out, int out_size, void* d_ws, size_t ws_size,
                              hipStream_t stream)
{
    const float* x  = (const float*)d_in[0];
    const float* h0 = (const float*)d_in[1];
    const float* W1 = (const float*)d_in[2];
    const float* b1 = (const float*)d_in[3];
    const float* W2 = (const float*)d_in[4];
    const float* b2 = (const float*)d_in[5];
    const float* Wg = (const float*)d_in[6];
    const float* Ug = (const float*)d_in[7];
    const float* bg = (const float*)d_in[8];
    const float* Wp = (const float*)d_in[9];
    const float* bp = (const float*)d_in[10];
    const float* Wv = (const float*)d_in[11];
    const float* bv = (const float*)d_in[12];

    char* ws = (char*)d_ws;
    __hip_bfloat16* W1b = (__hip_bfloat16*)(ws + 0);         // 2,097,152
    __hip_bfloat16* W2b = (__hip_bfloat16*)(ws + 2097152);   //   524,288
    __hip_bfloat16* Wgb = (__hip_bfloat16*)(ws + 2621440);   // 1,572,864
    __hip_bfloat16* z1b = (__hip_bfloat16*)(ws + 4194304);   // 8,388,608
    __hip_bfloat16* z2b = (__hip_bfloat16*)(ws + 12582912);  // 8,388,608
    float*          Xb  = (float*)(ws + 20971520);           // 50,331,648
    float*          seq = (float*)(ws + 71303168);           // 16,777,216
    unsigned long long* hbuf = (unsigned long long*)(ws + 88080384); // 8,192
    // hbuf needs NO init: step tags are self-validating vs 0xAA poison

    float* out = (float*)d_out;
    float* pol = out;
    float* val = out + (size_t)T_STEPS * AACT;
    float* hT  = out + (size_t)T_STEPS * AACT + T_STEPS;

    cast_f32_bf16<<<DIN * DD / 256, 256, 0, stream>>>(W1, W1b, DIN * DD);
    cast_f32_bf16<<<DD * DD / 256, 256, 0, stream>>>(W2, W2b, DD * DD);
    cast_f32_bf16<<<DD * H3 / 256, 256, 0, stream>>>(Wg, Wgb, DD * H3);

    dim3 blk(256);
    gemm_bf16<<<dim3(T_STEPS / 64, DD / 64), blk, 0, stream>>>(
        x, nullptr, W1b, b1, z1b, nullptr, T_STEPS, DD, DIN, 1);
    gemm_bf16<<<dim3(T_STEPS / 64, DD / 64), blk, 0, stream>>>(
        nullptr, z1b, W2b, b2, z2b, nullptr, T_STEPS, DD, DD, 1);
    gemm_bf16<<<dim3(T_STEPS / 64, H3 / 64), blk, 0, stream>>>(
        nullptr, z2b, Wgb, bg, nullptr, Xb, T_STEPS, H3, DD, 0);

    scan_kernel<<<NWG, 256, 0, stream>>>(Xb, Ug, bg, h0, seq, hbuf, hT);

    heads_kernel<<<T_STEPS, 64, 0, stream>>>(seq, Wp, bp, Wv, bv, pol, val);
}